// Round 6
// baseline (311.749 us; speedup 1.0000x reference)
//
#include <hip/hip_runtime.h>

// AttentionLayer: N=8, L=1024, D_MODEL=1024, H=16, d_head=64.
// out  = softmax(QK^T/8)V reshaped   (8,1024,1024) fp32
// attn = mean over heads of softmax  (8,1024,1024) fp32, after out.
//
// R9-R11 established: k2 is L2-SERVICE-BOUND. Time tracks per-XCD L2 bytes
// (R9: traffic/2 -> time/1.77; R10/R11 left traffic unchanged -> null).
// Current: 32 blocks/XCD x 6 MB (K + V + loop2 K) = 192 MB @ ~1.05 TB/s.
// R12: halve per-XCD traffic. 64 q-rows per block (grid 128, 16/XCD) via
// two head-phases; wave PAIRS (same head, q-halves) share one K/V stream
// staged per 32-s window into double-buffered LDS by global_load_lds
// (width 16, zero VGPRs), with XOR-swizzled GLOBAL SOURCE so swizzled
// ds_read_b128 (permuted K-frags, V-frags) are ~2-way conflict-free.
// Loop2 keeps direct global K (pair reads same lines -> L1 dedupe).
// Traffic: loop1 4 MB + loop2 ~4 MB per block -> ~104-128 MB/XCD.
// LDS: 128 KB arena (loop1 KV dbuf; loop2 attn stage aliased).
// ws: 32 MB (bKw + bTw).

#define NB 8
#define LQ 1024
#define DM 1024
#define NH 16
#define DH 64
#define AW2 34          // loop2 attn strip stride (shorts): 32 s + 2 pad

typedef __attribute__((ext_vector_type(4))) float f32x4;
typedef __attribute__((ext_vector_type(2))) float f32x2;
typedef __attribute__((ext_vector_type(8))) short bf16x8;
typedef __attribute__((ext_vector_type(4))) short bf16x4;
typedef __attribute__((ext_vector_type(4))) int   i32x4;
typedef __attribute__((ext_vector_type(2))) int   i32x2;

__device__ inline short f2bf(float f){
  unsigned u = __builtin_bit_cast(unsigned, f);
  u += 0x7fffu + ((u >> 16) & 1u);   // RNE (inputs finite)
  return (short)(u >> 16);
}
__device__ inline float bf2f(short s){
  unsigned u = ((unsigned)(unsigned short)s) << 16;
  return __builtin_bit_cast(float, u);
}
__device__ inline int cvt_pk_bf16(float lo, float hi){
  int r;
  asm("v_cvt_pk_bf16_f32 %0, %1, %2" : "=v"(r) : "v"(lo), "v"(hi));
  return r;
}
__device__ inline void gll16(const void* g, void* l){
  __builtin_amdgcn_global_load_lds(
    (const __attribute__((address_space(1))) unsigned int*)g,
    (__attribute__((address_space(3))) unsigned int*)l, 16, 0, 0);
}

// ---------------- k0: fp32 -> bf16 into MFMA-friendly layouts ---------------
__global__ __launch_bounds__(256) void k0_convert(const float* __restrict__ in,
                                                  short* __restrict__ bKw,
                                                  short* __restrict__ bTw){
  __shared__ short tile[32][36];
  int b  = blockIdx.x;
  int n  = b >> 10;
  int lt = (b >> 5) & 31;          // s-tile of 32 == V window index
  int dt = b & 31;                 // d-tile of 32: head = dt>>1, half = dt&1
  int r  = threadIdx.x >> 3;       // 0..31
  int c4 = (threadIdx.x & 7) << 2; // 0,4,...,28
  size_t src = ((size_t)(n*LQ + lt*32 + r))*DM + dt*32 + c4;
  f32x4 f = *(const f32x4*)(in + src);
  short s0 = f2bf(f.x), s1 = f2bf(f.y), s2 = f2bf(f.z), s3 = f2bf(f.w);
  // head-major K/Q: bKw[((n*16 + h)*1024 + s)*64 + (dt&1)*32 + c]
  bf16x4 pk = {s0, s1, s2, s3};
  size_t kdst = ((size_t)((n*NH + (dt >> 1))*LQ + lt*32 + r))*DH + (dt & 1)*32 + c4;
  *(bf16x4*)(bKw + kdst) = pk;
  // transpose for V
  tile[c4+0][r] = s0; tile[c4+1][r] = s1; tile[c4+2][r] = s2; tile[c4+3][r] = s3;
  __syncthreads();
  bf16x4 t = *(const bf16x4*)(&tile[r][c4]);
  // win-tiled V: bTw[((n*32 + lt)*1024 + dt*32 + r)*32 + sl]
  size_t vdst = ((size_t)((n*32 + lt)*DM + dt*32 + r))*32 + c4;
  *(bf16x4*)(bTw + vdst) = t;
}

// swizzle helpers (involutions on bits 4-6 / 4-5, row bits unaffected)
__device__ inline int swzK(int o){            // K window: 32 rows x 128 B
  int r = o >> 7;
  return o ^ (((r & 3) | (((r >> 3) & 1) << 2)) << 4);
}
__device__ inline int swzV(int o){            // V window: 64 rows x 64 B
  int d = o >> 6;
  return o ^ (((d >> 1) & 3) << 4);
}

#define QKEXP(K0, K1, DA0, DA1, DB0, DB1) do {                          \
    f32x4 stA = vzero, stB = vzero;                                     \
    stA = __builtin_amdgcn_mfma_f32_16x16x32_bf16(K0, qfA0, stA, 0,0,0);\
    stA = __builtin_amdgcn_mfma_f32_16x16x32_bf16(K1, qfA1, stA, 0,0,0);\
    stB = __builtin_amdgcn_mfma_f32_16x16x32_bf16(K0, qfB0, stB, 0,0,0);\
    stB = __builtin_amdgcn_mfma_f32_16x16x32_bf16(K1, qfB1, stB, 0,0,0);\
    float eA0 = __builtin_amdgcn_exp2f(stA[0]*CE);                      \
    float eA1 = __builtin_amdgcn_exp2f(stA[1]*CE);                      \
    float eA2 = __builtin_amdgcn_exp2f(stA[2]*CE);                      \
    float eA3 = __builtin_amdgcn_exp2f(stA[3]*CE);                      \
    float eB0 = __builtin_amdgcn_exp2f(stB[0]*CE);                      \
    float eB1 = __builtin_amdgcn_exp2f(stB[1]*CE);                      \
    float eB2 = __builtin_amdgcn_exp2f(stB[2]*CE);                      \
    float eB3 = __builtin_amdgcn_exp2f(stB[3]*CE);                      \
    rsumA += (eA0 + eA1) + (eA2 + eA3);                                 \
    rsumB += (eB0 + eB1) + (eB2 + eB3);                                 \
    DA0 = cvt_pk_bf16(eA0, eA1); DA1 = cvt_pk_bf16(eA2, eA3);           \
    DB0 = cvt_pk_bf16(eB0, eB1); DB1 = cvt_pk_bf16(eB2, eB3);           \
  } while(0)

// ---------------- k2: 16 waves = 8 pairs x 2 q-halves, 2 head-phases --------
__global__ __launch_bounds__(1024, 4) void k2_attn(const short* __restrict__ bKw,
                                                   const short* __restrict__ bTw,
                                                   float* __restrict__ out,
                                                   float* __restrict__ attn){
  __shared__ short ARENA[65536];        // 131072 B: loop1 KV dbuf / loop2 AS
  int tid  = threadIdx.x;
  int lane = tid & 63;
  int w    = tid >> 6;
  int p    = w >> 1;                    // pair id 0..7
  int half = w & 1;                     // q-half within pair
  int l16  = lane & 15;
  int quad = lane >> 4;
  int n  = blockIdx.x & 7;              // XCD swizzle: same-n blocks share L2
  int q0 = (blockIdx.x >> 3) << 6;      // 64 q-rows per block
  int q0w = q0 + half*32;               // this wave's 32 q-rows

  const float CE = 0.1803368801111244f; // 0.125 * log2(e)
  const f32x4 vzero = {0.f, 0.f, 0.f, 0.f};

  float irsA0, irsB0, irsA1, irsB1;

  auto phase = [&](int t, float& irsA_o, float& irsB_o){
    int h = p + 8*t;
    const short* kbstd = bKw + ((size_t)(n*NH + h))*LQ*DH + (size_t)l16*DH + quad*8;
    bf16x8 qfA0 = *(const bf16x8*)(kbstd + (size_t)q0w*DH);
    bf16x8 qfA1 = *(const bf16x8*)(kbstd + (size_t)q0w*DH + 32);
    bf16x8 qfB0 = *(const bf16x8*)(kbstd + (size_t)(q0w+16)*DH);
    bf16x8 qfB1 = *(const bf16x8*)(kbstd + (size_t)(q0w+16)*DH + 32);
    const char* kgw = (const char*)(bKw + ((size_t)(n*NH + h))*LQ*DH);
    const char* vgw = (const char*)(bTw + ((size_t)(n*32))*DM*32 + (size_t)h*64*32);

    // pair stages one K window (wave-even) + one V window (wave-odd),
    // pre-swizzled global source -> linear global_load_lds -> swizzled LDS
    auto stage = [&](int win, int buf){
      char* dst = (char*)ARENA + (size_t)(buf*8 + p)*8192;
      if (half == 0){
        const char* gs = kgw + (size_t)win*4096;
        #pragma unroll
        for (int j = 0; j < 4; ++j){
          int o = (j*64 + lane)*16;
          gll16(gs + swzK(o), dst + j*1024 + lane*16);
        }
      } else {
        const char* gs = vgw + (size_t)win*65536;
        char* vd = dst + 4096;
        #pragma unroll
        for (int j = 0; j < 4; ++j){
          int o = (j*64 + lane)*16;
          gll16(gs + swzV(o), vd + j*1024 + lane*16);
        }
      }
    };

    f32x4 oaccA[4], oaccB[4];
    #pragma unroll
    for (int dt = 0; dt < 4; ++dt){ oaccA[dt] = vzero; oaccB[dt] = vzero; }
    float rsumA = 0.f, rsumB = 0.f;

    int r0 = (l16 >> 2)*8 + (l16 & 3);  // permuted K-frag row (R10 trick)
    stage(0, 0);
    __syncthreads();
    for (int win = 0; win < 32; ++win){
      int buf = win & 1;
      if (win < 31) stage(win + 1, buf ^ 1);
      const char* kreg = (const char*)ARENA + (size_t)(buf*8 + p)*8192;
      const char* vreg = kreg + 4096;
      int ra = r0, rb = r0 + 4;
      int swa = ((ra & 3) | (((ra >> 3) & 1) << 2)) << 4;
      int swb = ((rb & 3) | (((rb >> 3) & 1) << 2)) << 4;
      bf16x8 kf0 = *(const bf16x8*)(kreg + ((ra*128 + quad*16) ^ swa));
      bf16x8 kf1 = *(const bf16x8*)(kreg + ((ra*128 + 64 + quad*16) ^ swa));
      bf16x8 kf2 = *(const bf16x8*)(kreg + ((rb*128 + quad*16) ^ swb));
      bf16x8 kf3 = *(const bf16x8*)(kreg + ((rb*128 + 64 + quad*16) ^ swb));
      int paA0, paA1, paB0, paB1, dA0, dA1, dB0, dB1;
      QKEXP(kf0, kf1, paA0, paA1, paB0, paB1);   // s = quad*8 + 0..3
      QKEXP(kf2, kf3, dA0, dA1, dB0, dB1);       // s = quad*8 + 4..7
      i32x4 ta = {paA0, paA1, dA0, dA1};
      i32x4 tb = {paB0, paB1, dB0, dB1};
      bf16x8 aA = __builtin_bit_cast(bf16x8, ta);
      bf16x8 aB = __builtin_bit_cast(bf16x8, tb);
      bf16x8 vf0, vf1, vf2, vf3;
      {
        int d0 = l16,      d1 = 16 + l16, d2 = 32 + l16, d3 = 48 + l16;
        vf0 = *(const bf16x8*)(vreg + ((d0*64 + quad*16) ^ (((d0 >> 1) & 3) << 4)));
        vf1 = *(const bf16x8*)(vreg + ((d1*64 + quad*16) ^ (((d1 >> 1) & 3) << 4)));
        vf2 = *(const bf16x8*)(vreg + ((d2*64 + quad*16) ^ (((d2 >> 1) & 3) << 4)));
        vf3 = *(const bf16x8*)(vreg + ((d3*64 + quad*16) ^ (((d3 >> 1) & 3) << 4)));
      }
      oaccA[0] = __builtin_amdgcn_mfma_f32_16x16x32_bf16(aA, vf0, oaccA[0], 0,0,0);
      oaccB[0] = __builtin_amdgcn_mfma_f32_16x16x32_bf16(aB, vf0, oaccB[0], 0,0,0);
      oaccA[1] = __builtin_amdgcn_mfma_f32_16x16x32_bf16(aA, vf1, oaccA[1], 0,0,0);
      oaccB[1] = __builtin_amdgcn_mfma_f32_16x16x32_bf16(aB, vf1, oaccB[1], 0,0,0);
      oaccA[2] = __builtin_amdgcn_mfma_f32_16x16x32_bf16(aA, vf2, oaccA[2], 0,0,0);
      oaccB[2] = __builtin_amdgcn_mfma_f32_16x16x32_bf16(aB, vf2, oaccB[2], 0,0,0);
      oaccA[3] = __builtin_amdgcn_mfma_f32_16x16x32_bf16(aA, vf3, oaccA[3], 0,0,0);
      oaccB[3] = __builtin_amdgcn_mfma_f32_16x16x32_bf16(aB, vf3, oaccB[3], 0,0,0);
      __syncthreads();
    }

    // softmax normalizer for q = q0w + l16 (sum across quads)
    rsumA += __shfl_xor(rsumA, 16);
    rsumA += __shfl_xor(rsumA, 32);
    rsumB += __shfl_xor(rsumB, 16);
    rsumB += __shfl_xor(rsumB, 32);
    float irA = 1.0f / rsumA;
    float irB = 1.0f / rsumB;
    float irqA[4], irqB[4];
    #pragma unroll
    for (int j = 0; j < 4; ++j){
      irqA[j] = __shfl(irA, quad*4 + j);
      irqB[j] = __shfl(irB, quad*4 + j);
    }
    #pragma unroll
    for (int dt = 0; dt < 4; ++dt){
      float* opA = out + ((size_t)(n*LQ + q0w + quad*4))*DM + h*DH + dt*16 + l16;
      opA[0]    = oaccA[dt][0] * irqA[0];
      opA[DM]   = oaccA[dt][1] * irqA[1];
      opA[2*DM] = oaccA[dt][2] * irqA[2];
      opA[3*DM] = oaccA[dt][3] * irqA[3];
      float* opB = opA + (size_t)16*DM;
      opB[0]    = oaccB[dt][0] * irqB[0];
      opB[DM]   = oaccB[dt][1] * irqB[1];
      opB[2*DM] = oaccB[dt][2] * irqB[2];
      opB[3*DM] = oaccB[dt][3] * irqB[3];
    }
    irsA_o = irA * 0.0625f;
    irsB_o = irB * 0.0625f;
  };

  phase(0, irsA0, irsB0);
  phase(1, irsA1, irsB1);

  // ---- loop2: recompute QK per 32-s strip for both phase heads, reduce ----
  int h0 = p, h1 = p + 8;
  const short* kb0 = bKw + ((size_t)(n*NH + h0))*LQ*DH + (size_t)l16*DH + quad*8;
  const short* kb1 = bKw + ((size_t)(n*NH + h1))*LQ*DH + (size_t)l16*DH + quad*8;
  bf16x8 q0A0 = *(const bf16x8*)(kb0 + (size_t)q0w*DH);
  bf16x8 q0A1 = *(const bf16x8*)(kb0 + (size_t)q0w*DH + 32);
  bf16x8 q0B0 = *(const bf16x8*)(kb0 + (size_t)(q0w+16)*DH);
  bf16x8 q0B1 = *(const bf16x8*)(kb0 + (size_t)(q0w+16)*DH + 32);
  bf16x8 q1A0 = *(const bf16x8*)(kb1 + (size_t)q0w*DH);
  bf16x8 q1A1 = *(const bf16x8*)(kb1 + (size_t)q0w*DH + 32);
  bf16x8 q1B0 = *(const bf16x8*)(kb1 + (size_t)(q0w+16)*DH);
  bf16x8 q1B1 = *(const bf16x8*)(kb1 + (size_t)(q0w+16)*DH + 32);

  auto stage2 = [&](const short* kb, bf16x8 qA0, bf16x8 qA1, bf16x8 qB0, bf16x8 qB1,
                    float irsA, float irsB, int h, int win){
    #pragma unroll
    for (int fp = 0; fp < 2; ++fp){
      const short* kp = kb + (size_t)(win*32 + fp*16)*DH;
      bf16x8 k0 = *(const bf16x8*)kp;
      bf16x8 k1 = *(const bf16x8*)(kp + 32);
      f32x4 stA = vzero, stB = vzero;
      stA = __builtin_amdgcn_mfma_f32_16x16x32_bf16(k0, qA0, stA, 0,0,0);
      stA = __builtin_amdgcn_mfma_f32_16x16x32_bf16(k1, qA1, stA, 0,0,0);
      stB = __builtin_amdgcn_mfma_f32_16x16x32_bf16(k0, qB0, stB, 0,0,0);
      stB = __builtin_amdgcn_mfma_f32_16x16x32_bf16(k1, qB1, stB, 0,0,0);
      float gA0 = __builtin_amdgcn_exp2f(stA[0]*CE) * irsA;
      float gA1 = __builtin_amdgcn_exp2f(stA[1]*CE) * irsA;
      float gA2 = __builtin_amdgcn_exp2f(stA[2]*CE) * irsA;
      float gA3 = __builtin_amdgcn_exp2f(stA[3]*CE) * irsA;
      float gB0 = __builtin_amdgcn_exp2f(stB[0]*CE) * irsB;
      float gB1 = __builtin_amdgcn_exp2f(stB[1]*CE) * irsB;
      float gB2 = __builtin_amdgcn_exp2f(stB[2]*CE) * irsB;
      float gB3 = __builtin_amdgcn_exp2f(stB[3]*CE) * irsB;
      i32x2 wvA = {cvt_pk_bf16(gA0, gA1), cvt_pk_bf16(gA2, gA3)};
      i32x2 wvB = {cvt_pk_bf16(gB0, gB1), cvt_pk_bf16(gB2, gB3)};
      int qlA = half*32 + l16;
      *(i32x2*)(&ARENA[(h*64 + qlA)*AW2 + fp*16 + quad*4])      = wvA;
      *(i32x2*)(&ARENA[(h*64 + qlA + 16)*AW2 + fp*16 + quad*4]) = wvB;
    }
  };

  for (int win = 0; win < 32; ++win){
    stage2(kb0, q0A0, q0A1, q0B0, q0B1, irsA0, irsB0, h0, win);
    stage2(kb1, q1A0, q1A1, q1B0, q1B1, irsA1, irsB1, h1, win);
    __syncthreads();
    {
      int q  = tid >> 4;                // 0..63
      int s2 = tid & 15;                // s pair: s = 2*s2
      float s0 = 0.f, s1 = 0.f;
      #pragma unroll
      for (int hh = 0; hh < NH; ++hh){
        int v = *(const int*)(&ARENA[(hh*64 + q)*AW2 + 2*s2]);
        s0 += bf2f((short)(v & 0xffff));
        s1 += bf2f((short)((unsigned)v >> 16));
      }
      f32x2 ov = {s0, s1};
      *(f32x2*)(&attn[((size_t)(n*LQ + q0 + q))*LQ + win*32 + 2*s2]) = ov;
    }
    __syncthreads();
  }
}

extern "C" void kernel_launch(void* const* d_in, const int* in_sizes, int n_in,
                              void* d_out, int out_size, void* d_ws, size_t ws_size,
                              hipStream_t stream){
  const float* in = (const float*)d_in[0];
  float* out  = (float*)d_out;
  float* attn = out + (size_t)NB*LQ*DM;
  short* bKw = (short*)d_ws;
  short* bTw = bKw + (size_t)NB*LQ*DM;

  k0_convert<<<dim3(8192), dim3(256),  0, stream>>>(in, bKw, bTw);
  k2_attn   <<<dim3(128),  dim3(1024), 0, stream>>>(bKw, bTw, out, attn);
}

// Round 7
// 251.130 us; speedup vs baseline: 1.2414x; 1.2414x over previous
//
#include <hip/hip_runtime.h>

// AttentionLayer: N=8, L=1024, D_MODEL=1024, H=16, d_head=64.
// out  = softmax(QK^T/8)V reshaped   (8,1024,1024) fp32
// attn = mean over heads of softmax  (8,1024,1024) fp32, after out.
//
// R10: k2 = 180us plateau (latency-bound; R11 prefetch null, R12 traffic
//      cut regressed via half-idle machine -> L2-bound model falsified).
// R13: k2 reverted to the verified R10 version. Target the OTHER 70us:
//      total - k2 == ~70us across R9-R11 == k0 + overhead (roofline ~10us).
//      Old k0: 8192 tiny blocks, 64B-segment strided stores. New k0:
//      512 blocks x 256 thr, one per (n, win, d-half); 32x512 bf16 LDS tile
//      (33KB, 4 blocks/CU); bKw written as 1KB-contiguous wave-passes
//      (8 rows x 128B), bTw transposed via u16 LDS gathers into 1KB-
//      contiguous wave-passes. All stores 16B/lane coalesced. Numerics
//      bit-identical (same RNE cvt): absmax tripwire 0.046875.
// ws: 32 MB (bKw + bTw).

#define NB 8
#define LQ 1024
#define DM 1024
#define NH 16
#define DH 64
#define AW 68           // attn stage row stride (shorts): 136 B
#define TR 528          // k0 LDS row stride (shorts): 16B-multiple, 33 KB tile

typedef __attribute__((ext_vector_type(4))) float f32x4;
typedef __attribute__((ext_vector_type(8))) short bf16x8;
typedef __attribute__((ext_vector_type(4))) short bf16x4;
typedef __attribute__((ext_vector_type(4))) int   i32x4;
typedef __attribute__((ext_vector_type(2))) int   i32x2;

__device__ inline short f2bf(float f){
  unsigned u = __builtin_bit_cast(unsigned, f);
  u += 0x7fffu + ((u >> 16) & 1u);   // RNE (inputs finite)
  return (short)(u >> 16);
}
__device__ inline float bf2f(short s){
  unsigned u = ((unsigned)(unsigned short)s) << 16;
  return __builtin_bit_cast(float, u);
}
__device__ inline int cvt_pk_bf16(float lo, float hi){
  int r;
  asm("v_cvt_pk_bf16_f32 %0, %1, %2" : "=v"(r) : "v"(lo), "v"(hi));
  return r;
}

// ---------------- k0: fp32 -> bf16, coalesced writes ------------------------
// block b = (n*32 + win)*2 + dh; 256 threads; LDS tile T[32 s][512 d-local].
__global__ __launch_bounds__(256) void k0_convert(const float* __restrict__ in,
                                                  short* __restrict__ bKw,
                                                  short* __restrict__ bTw){
  __shared__ short T[32*TR];
  int b   = blockIdx.x;
  int dh  = b & 1;                 // d-half: d in [dh*512, dh*512+512)
  int win = (b >> 1) & 31;         // 32-s window
  int n   = b >> 6;
  int tid = threadIdx.x;
  int w    = tid >> 6;
  int lane = tid & 63;

  // step 1: coalesced read + convert + LDS store
  {
    int s  = tid >> 3;             // 0..31
    int c0 = (tid & 7) << 2;       // f32 col base within 32-col stripe
    const float* src = in + ((size_t)(n*LQ + win*32 + s))*DM + dh*512;
    #pragma unroll
    for (int p = 0; p < 16; ++p){
      int c = p*32 + c0;
      f32x4 f = *(const f32x4*)(src + c);
      bf16x4 v = {f2bf(f.x), f2bf(f.y), f2bf(f.z), f2bf(f.w)};
      *(bf16x4*)&T[s*TR + c] = v;
    }
  }
  __syncthreads();

  // step 2: bKw -- heads h = dh*8 + hl; per head 32 rows x 128 B contiguous.
  // task t = pass*4 + w: hl = t>>2, rowgroup rg = t&3; wave-pass writes
  // 8 rows x 128 B = 1 KB contiguous.
  {
    int r8 = lane >> 3;            // row within group
    int cc = (lane & 7) << 3;      // 8 shorts = 16 B
    #pragma unroll
    for (int pass = 0; pass < 8; ++pass){
      int t  = pass*4 + w;         // 0..31
      int hl = t >> 2;             // 0..7
      int rg = t & 3;              // 0..3
      int s  = rg*8 + r8;
      bf16x8 v = *(const bf16x8*)&T[s*TR + hl*64 + cc];
      int h = dh*8 + hl;
      size_t dst = ((size_t)((n*NH + h)*LQ + win*32 + s))*DH + cc;
      *(bf16x8*)(bKw + dst) = v;
    }
  }

  // step 3: bTw -- transpose. lane covers (d = t*16 + lane>>2, sl8 = (lane&3)*8);
  // wave-pass writes 16 d x 64 B = 1 KB contiguous.
  {
    #pragma unroll
    for (int pass = 0; pass < 8; ++pass){
      int t    = pass*4 + w;       // 0..31
      int dloc = t*16 + (lane >> 2);
      int sl8  = (lane & 3) << 3;
      short t0 = T[(sl8+0)*TR + dloc];
      short t1 = T[(sl8+1)*TR + dloc];
      short t2 = T[(sl8+2)*TR + dloc];
      short t3 = T[(sl8+3)*TR + dloc];
      short t4 = T[(sl8+4)*TR + dloc];
      short t5 = T[(sl8+5)*TR + dloc];
      short t6 = T[(sl8+6)*TR + dloc];
      short t7 = T[(sl8+7)*TR + dloc];
      bf16x8 v = {t0, t1, t2, t3, t4, t5, t6, t7};
      int d = dh*512 + dloc;
      size_t dst = ((size_t)((n*32 + win)*DM + d))*32 + sl8;
      *(bf16x8*)(bTw + dst) = v;
    }
  }
}

// ---------------- k2: one wave per head, two q-tiles per wave (R10) ---------
// LDS arena AS[2][NH*16*AW] shorts (69632 B): loop2 attn staging only.
__global__ __launch_bounds__(1024, 4) void k2_attn(const short* __restrict__ bKw,
                                                   const short* __restrict__ bTw,
                                                   float* __restrict__ out,
                                                   float* __restrict__ attn){
  __shared__ short AS[2*NH*16*AW];      // 69632 B
  int tid  = threadIdx.x;
  int lane = tid & 63;
  int w    = tid >> 6;                  // wave id == head id
  int l16  = lane & 15;
  int quad = lane >> 4;
  int n  = blockIdx.x & 7;              // XCD swizzle: all blocks on XCD x share n=x
  int q0 = (blockIdx.x >> 3) << 5;      // 32 q-rows per block

  const float CE = 0.1803368801111244f; // 0.125 * log2(e)
  const f32x4 vzero = {0.f, 0.f, 0.f, 0.f};

  size_t hb = ((size_t)(n*NH + w))*LQ*DH;
  // standard fragment base (Q loads, loop2 K loads): row s -> kb + s*64
  const short* kb  = bKw + hb + (size_t)l16*DH + quad*8;
  // permuted fragment base (loop1 K loads): lane l16=r supplies row (r>>2)*8+(r&3)
  const short* kbp = bKw + hb + (size_t)((l16 >> 2)*8 + (l16 & 3))*DH + quad*8;

  bf16x8 qfA0 = *(const bf16x8*)(kb + (size_t)q0*DH);
  bf16x8 qfA1 = *(const bf16x8*)(kb + (size_t)q0*DH + 32);
  bf16x8 qfB0 = *(const bf16x8*)(kb + (size_t)(q0+16)*DH);
  bf16x8 qfB1 = *(const bf16x8*)(kb + (size_t)(q0+16)*DH + 32);

  f32x4 oaccA[4], oaccB[4];
  #pragma unroll
  for (int dt = 0; dt < 4; ++dt){ oaccA[dt] = vzero; oaccB[dt] = vzero; }
  float rsumA = 0.f, rsumB = 0.f;

  // ---- loop1: QK + exp (unnormalized) + PV, no barriers, no LDS ----
  // fragment f: s-offset t = (f>>1)*32 + (f&1)*4; covers rows t + perm set.
  bf16x8 kf0 = *(const bf16x8*)kbp;            // f=0 -> t=0
  bf16x8 kf1 = *(const bf16x8*)(kbp + 32);
  bf16x8 vpre[4];
  int paA0 = 0, paA1 = 0, paB0 = 0, paB1 = 0;  // packed bf16 from even f
  for (int f = 0; f < 64; ++f){
    int fn = (f + 1) & 63;
    int tn = (fn >> 1)*32 + (fn & 1)*4;
    const short* nkp = kbp + (size_t)tn*DH;
    bf16x8 nkf0 = *(const bf16x8*)nkp;
    bf16x8 nkf1 = *(const bf16x8*)(nkp + 32);
    if ((f & 1) == 0){
      // prefetch V for the 32-s window consumed at the next (odd) f
      int vwin = f >> 1;
      #pragma unroll
      for (int dt = 0; dt < 4; ++dt){
        const short* vp = bTw + ((size_t)((n*32 + vwin)*DM + w*DH + dt*16 + l16))*32 + quad*8;
        vpre[dt] = *(const bf16x8*)vp;
      }
    }
    f32x4 stA = vzero, stB = vzero;
    stA = __builtin_amdgcn_mfma_f32_16x16x32_bf16(kf0, qfA0, stA, 0, 0, 0);
    stA = __builtin_amdgcn_mfma_f32_16x16x32_bf16(kf1, qfA1, stA, 0, 0, 0);
    stB = __builtin_amdgcn_mfma_f32_16x16x32_bf16(kf0, qfB0, stB, 0, 0, 0);
    stB = __builtin_amdgcn_mfma_f32_16x16x32_bf16(kf1, qfB1, stB, 0, 0, 0);
    float eA0 = __builtin_amdgcn_exp2f(stA[0]*CE);
    float eA1 = __builtin_amdgcn_exp2f(stA[1]*CE);
    float eA2 = __builtin_amdgcn_exp2f(stA[2]*CE);
    float eA3 = __builtin_amdgcn_exp2f(stA[3]*CE);
    float eB0 = __builtin_amdgcn_exp2f(stB[0]*CE);
    float eB1 = __builtin_amdgcn_exp2f(stB[1]*CE);
    float eB2 = __builtin_amdgcn_exp2f(stB[2]*CE);
    float eB3 = __builtin_amdgcn_exp2f(stB[3]*CE);
    rsumA += (eA0 + eA1) + (eA2 + eA3);
    rsumB += (eB0 + eB1) + (eB2 + eB3);
    int dA0 = cvt_pk_bf16(eA0, eA1), dA1 = cvt_pk_bf16(eA2, eA3);
    int dB0 = cvt_pk_bf16(eB0, eB1), dB1 = cvt_pk_bf16(eB2, eB3);
    if ((f & 1) == 0){
      paA0 = dA0; paA1 = dA1; paB0 = dB0; paB1 = dB1;
    } else {
      // A-fragment k=quad*8+j: elems 0-3 from even f (s+0..3), 4-7 odd (s+4..7)
      i32x4 ta = {paA0, paA1, dA0, dA1};
      i32x4 tb = {paB0, paB1, dB0, dB1};
      bf16x8 a01A = __builtin_bit_cast(bf16x8, ta);
      bf16x8 a01B = __builtin_bit_cast(bf16x8, tb);
      #pragma unroll
      for (int dt = 0; dt < 4; ++dt){
        oaccA[dt] = __builtin_amdgcn_mfma_f32_16x16x32_bf16(a01A, vpre[dt], oaccA[dt], 0, 0, 0);
        oaccB[dt] = __builtin_amdgcn_mfma_f32_16x16x32_bf16(a01B, vpre[dt], oaccB[dt], 0, 0, 0);
      }
    }
    kf0 = nkf0; kf1 = nkf1;
  }

  // softmax normalizer for q = l16 (full row sum across quads)
  rsumA += __shfl_xor(rsumA, 16);
  rsumA += __shfl_xor(rsumA, 32);
  rsumB += __shfl_xor(rsumB, 16);
  rsumB += __shfl_xor(rsumB, 32);
  float irA  = 1.0f / rsumA;
  float irB  = 1.0f / rsumB;
  float irsA = irA * 0.0625f;           // folded 1/NH for attn
  float irsB = irB * 0.0625f;

  // ---- O epilogue: oacc rows are q = quad*4 + j -> need ir of that q ----
  float irqA[4], irqB[4];
  #pragma unroll
  for (int j = 0; j < 4; ++j){
    irqA[j] = __shfl(irA, quad*4 + j);
    irqB[j] = __shfl(irB, quad*4 + j);
  }
  #pragma unroll
  for (int dt = 0; dt < 4; ++dt){
    float* opA = out + ((size_t)(n*LQ + q0 + quad*4))*DM + w*DH + dt*16 + l16;
    opA[0]      = oaccA[dt][0] * irqA[0];
    opA[DM]     = oaccA[dt][1] * irqA[1];
    opA[2*DM]   = oaccA[dt][2] * irqA[2];
    opA[3*DM]   = oaccA[dt][3] * irqA[3];
    float* opB = opA + (size_t)16*DM;
    opB[0]      = oaccB[dt][0] * irqB[0];
    opB[DM]     = oaccB[dt][1] * irqB[1];
    opB[2*DM]   = oaccB[dt][2] * irqB[2];
    opB[3*DM]   = oaccB[dt][3] * irqB[3];
  }

  // ---- loop2: recompute QK per 64-s window, bf16 attn stage + reduce ----
  short* AmineA = &AS[w*16*AW];
  short* AmineB = &AS[NH*16*AW + w*16*AW];
  for (int win = 0; win < 16; ++win){
    bf16x8 kw[4][2];
    #pragma unroll
    for (int sub = 0; sub < 4; ++sub){
      const short* kp = kb + (size_t)(win*64 + sub*16)*DH;
      kw[sub][0] = *(const bf16x8*)kp;
      kw[sub][1] = *(const bf16x8*)(kp + 32);
    }
    #pragma unroll
    for (int sub = 0; sub < 4; ++sub){
      f32x4 stA = vzero, stB = vzero;
      stA = __builtin_amdgcn_mfma_f32_16x16x32_bf16(kw[sub][0], qfA0, stA, 0, 0, 0);
      stA = __builtin_amdgcn_mfma_f32_16x16x32_bf16(kw[sub][1], qfA1, stA, 0, 0, 0);
      stB = __builtin_amdgcn_mfma_f32_16x16x32_bf16(kw[sub][0], qfB0, stB, 0, 0, 0);
      stB = __builtin_amdgcn_mfma_f32_16x16x32_bf16(kw[sub][1], qfB1, stB, 0, 0, 0);
      float gA0 = __builtin_amdgcn_exp2f(stA[0]*CE) * irsA;
      float gA1 = __builtin_amdgcn_exp2f(stA[1]*CE) * irsA;
      float gA2 = __builtin_amdgcn_exp2f(stA[2]*CE) * irsA;
      float gA3 = __builtin_amdgcn_exp2f(stA[3]*CE) * irsA;
      float gB0 = __builtin_amdgcn_exp2f(stB[0]*CE) * irsB;
      float gB1 = __builtin_amdgcn_exp2f(stB[1]*CE) * irsB;
      float gB2 = __builtin_amdgcn_exp2f(stB[2]*CE) * irsB;
      float gB3 = __builtin_amdgcn_exp2f(stB[3]*CE) * irsB;
      i32x2 wvA = {cvt_pk_bf16(gA0, gA1), cvt_pk_bf16(gA2, gA3)};
      i32x2 wvB = {cvt_pk_bf16(gB0, gB1), cvt_pk_bf16(gB2, gB3)};
      *(i32x2*)(&AmineA[l16*AW + sub*16 + quad*4]) = wvA;
      *(i32x2*)(&AmineB[l16*AW + sub*16 + quad*4]) = wvB;
    }
    __syncthreads();
    {
      int qr = tid >> 6;                // 0..15
      int s  = tid & 63;                // 0..63
      float sum0 = 0.f, sum1 = 0.f;
      #pragma unroll
      for (int ww = 0; ww < NH; ++ww){
        sum0 += bf2f(AS[ww*16*AW + qr*AW + s]);
        sum1 += bf2f(AS[NH*16*AW + ww*16*AW + qr*AW + s]);
      }
      attn[((size_t)(n*LQ + q0 + qr))*LQ + win*64 + s]      = sum0;
      attn[((size_t)(n*LQ + q0 + 16 + qr))*LQ + win*64 + s] = sum1;
    }
    __syncthreads();
  }
}

extern "C" void kernel_launch(void* const* d_in, const int* in_sizes, int n_in,
                              void* d_out, int out_size, void* d_ws, size_t ws_size,
                              hipStream_t stream){
  const float* in = (const float*)d_in[0];
  float* out  = (float*)d_out;
  float* attn = out + (size_t)NB*LQ*DM;
  short* bKw = (short*)d_ws;
  short* bTw = bKw + (size_t)NB*LQ*DM;

  k0_convert<<<dim3(512), dim3(256),  0, stream>>>(in, bKw, bTw);
  k2_attn   <<<dim3(256), dim3(1024), 0, stream>>>(bKw, bTw, out, attn);
}